// Round 1
// 488.414 us; speedup vs baseline: 1.0365x; 1.0365x over previous
//
#include <hip/hip_runtime.h>
#include <hip/hip_bf16.h>
#include <stdint.h>

#define B_ 32
#define S_ 2048
#define H_ 768
#define E_ 2

typedef float f32x4 __attribute__((ext_vector_type(4)));
typedef short bf16x8 __attribute__((ext_vector_type(8)));

typedef const __attribute__((address_space(1))) void* gas_cvptr;
typedef __attribute__((address_space(3))) void* las_vptr;

__device__ __forceinline__ unsigned short f2bf(float f) {
    union { float f; uint32_t u; } v; v.f = f;
    uint32_t r = v.u + 0x7fffu + ((v.u >> 16) & 1u);  // RNE
    return (unsigned short)(r >> 16);
}

// ---------------- Kernel 1: fp32 -> bf16 convert + seq-sum reduce ----------------
// grid: 32*64 blocks of 192 threads. Block (b, sc) handles 32 s-rows.
__global__ __launch_bounds__(192) void convert_reduce(
    const float* __restrict__ in, unsigned short* __restrict__ xbf,
    float* __restrict__ seq_sum)
{
    const int b  = blockIdx.x >> 6;
    const int sc = blockIdx.x & 63;
    const int t  = threadIdx.x;            // 0..191, covers 768/4 float4 columns
    float sx = 0.f, sy = 0.f, sz = 0.f, sw = 0.f;
    const int s0 = sc * 32;
#pragma unroll 4
    for (int s = s0; s < s0 + 32; ++s) {
        size_t ro = ((size_t)b * S_ + s) * (H_ / 4) + t;
        float4 v = ((const float4*)in)[ro];
        sx += v.x; sy += v.y; sz += v.z; sw += v.w;
        ushort4 o;
        o.x = f2bf(v.x); o.y = f2bf(v.y); o.z = f2bf(v.z); o.w = f2bf(v.w);
        ((ushort4*)xbf)[ro] = o;
    }
    float* dst = seq_sum + b * H_ + t * 4;
    atomicAdd(dst + 0, sx);
    atomicAdd(dst + 1, sy);
    atomicAdd(dst + 2, sz);
    atomicAdd(dst + 3, sw);
}

// ---------------- Kernel 2: expert_w [e][k][n] fp32 -> wt [e][n][k] bf16 ----------------
__global__ __launch_bounds__(256) void transpose_w(
    const float* __restrict__ w, unsigned short* __restrict__ wt)
{
    __shared__ float tile[64][65];
    const int tn = blockIdx.x, tk = blockIdx.y, e = blockIdx.z;
    const int t = threadIdx.x;
    const float* wb = w + (size_t)e * H_ * H_;
#pragma unroll
    for (int j = 0; j < 16; ++j) {
        int idx = j * 256 + t;
        int r = idx >> 6, c = idx & 63;      // r = k_local, c = n_local
        tile[r][c] = wb[(size_t)(tk * 64 + r) * H_ + tn * 64 + c];
    }
    __syncthreads();
    unsigned short* wtb = wt + (size_t)e * H_ * H_;
#pragma unroll
    for (int j = 0; j < 16; ++j) {
        int idx = j * 256 + t;
        int r = idx >> 6, c = idx & 63;      // r = n_local, c = k_local
        wtb[(size_t)(tn * 64 + r) * H_ + tk * 64 + c] = f2bf(tile[c][r]);
    }
}

// ---------------- Kernel 3: router (LN -> logits -> softmax -> argmax) ----------------
__global__ __launch_bounds__(256) void router_kernel(
    const float* __restrict__ seq_sum, const float* __restrict__ gamma,
    const float* __restrict__ beta, const float* __restrict__ rw,
    const float* __restrict__ rb, int* __restrict__ eidx, float* __restrict__ psum)
{
    const int b = blockIdx.x;
    const int t = threadIdx.x;
    const int wave = t >> 6, lane = t & 63;
    __shared__ float red[8];
    float x[3];
    float s1 = 0.f, s2 = 0.f;
#pragma unroll
    for (int c = 0; c < 3; ++c) {
        int h = t + c * 256;
        float v = seq_sum[b * H_ + h] * (1.0f / (float)S_);
        x[c] = v; s1 += v; s2 += v * v;
    }
#pragma unroll
    for (int off = 32; off > 0; off >>= 1) {
        s1 += __shfl_down(s1, off, 64);
        s2 += __shfl_down(s2, off, 64);
    }
    if (lane == 0) { red[wave] = s1; red[4 + wave] = s2; }
    __syncthreads();
    s1 = red[0] + red[1] + red[2] + red[3];
    s2 = red[4] + red[5] + red[6] + red[7];
    const float mu = s1 * (1.0f / (float)H_);
    const float var = s2 * (1.0f / (float)H_) - mu * mu;
    const float rstd = rsqrtf(var + 1e-5f);
    float l0 = 0.f, l1 = 0.f;
#pragma unroll
    for (int c = 0; c < 3; ++c) {
        int h = t + c * 256;
        float nrm = (x[c] - mu) * rstd * gamma[h] + beta[h];
        l0 += nrm * rw[h * 2 + 0];
        l1 += nrm * rw[h * 2 + 1];
    }
    __syncthreads();   // red[] reuse
#pragma unroll
    for (int off = 32; off > 0; off >>= 1) {
        l0 += __shfl_down(l0, off, 64);
        l1 += __shfl_down(l1, off, 64);
    }
    if (lane == 0) { red[wave] = l0; red[4 + wave] = l1; }
    __syncthreads();
    if (t == 0) {
        l0 = red[0] + red[1] + red[2] + red[3] + rb[0];
        l1 = red[4] + red[5] + red[6] + red[7] + rb[1];
        float m = fmaxf(l0, l1);
        float p0 = expf(l0 - m), p1 = expf(l1 - m);
        float z = p0 + p1; p0 /= z; p1 /= z;
        eidx[b] = (l1 > l0) ? 1 : 0;
        atomicAdd(&psum[0], p0);
        atomicAdd(&psum[1], p1);
    }
}

// ---------------- Kernel 4: expert GEMM + bias + GELU (2-phase dbuf pipeline) ----------------
// C[b] = GELU(X[b] @ W[e(b)] + bias[e(b)]) ; X bf16 [2048,768], W^T bf16 [768n,768k]
// 128x128 tile, BK=64, 4 waves of 64x64, 16x16x32 MFMA.
// - XCD-chunked 1D-grid swizzle: the 6 bn-blocks sharing one (b,bm) A-panel are
//   adjacent on the SAME XCD -> A re-reads hit that XCD's L2 (was 3.2x HBM fetch).
// - Double-buffered LDS (64 KB) + counted s_waitcnt vmcnt(8): next K-tile's
//   global_load_lds stay in flight across the barrier; vmcnt never drains to 0
//   in the main loop (T3/T4 minimum recipe).
// - LDS is XOR-chunk-swizzled exactly as before (conflict-free ds_read_b128).
__global__ __launch_bounds__(256, 2) void moe_gemm(
    const unsigned short* __restrict__ xbf, const unsigned short* __restrict__ wt,
    const float* __restrict__ eb, const int* __restrict__ eidx,
    const float* __restrict__ psum, float* __restrict__ out,
    float* __restrict__ out_aux)
{
    // ---- XCD-chunked bijective swizzle (3072 blocks = 8 XCDs * 384) ----
    const int h    = blockIdx.x;
    const int slot = (h >> 3) + (h & 7) * 384;
    const int b    = slot / 96;            // 0..31 (4 consecutive b per XCD)
    const int rr   = slot - b * 96;
    const int bm   = rr / 6;               // 0..15
    const int bn   = rr - bm * 6;          // 0..5  (6 bn-siblings adjacent)

    const int tid  = threadIdx.x;
    const int wave = tid >> 6;
    const int lane = tid & 63;
    const int e = eidx[b];

    // fold former aux_kernel into block 0 (runs concurrent with GEMM work)
    if (h == 0 && tid == 0) {
        float a0 = psum[0] * (1.0f / (float)B_) - 0.5f;
        float a1 = psum[1] * (1.0f / (float)B_) - 0.5f;
        out_aux[0] = 0.01f * 0.5f * (a0 * a0 + a1 * a1);
    }

    const unsigned short* Abase = xbf + (size_t)b * S_ * H_;
    const unsigned short* Bbase = wt  + (size_t)e * H_ * H_;

    __shared__ unsigned short lds_A[2][128 * 64];   // [m][k], chunk-swizzled
    __shared__ unsigned short lds_B[2][128 * 64];   // [n][k], chunk-swizzled

    f32x4 acc[4][4];
#pragma unroll
    for (int i = 0; i < 4; ++i)
#pragma unroll
        for (int j = 0; j < 4; ++j)
            acc[i][j] = (f32x4){0.f, 0.f, 0.f, 0.f};

    const int wm = (wave & 1) * 64;
    const int wn = (wave >> 1) * 64;
    const int rin = lane >> 3;           // row within 8-row staging inst
    const int chk = lane & 7;            // 16B chunk within row (LDS slot)
    const int schk = chk ^ rin;          // XOR-swizzled source chunk

    // issue the 8 global_load_lds for one K-tile (per wave: 4x A + 4x B)
    auto stage = [&](unsigned short* dA, unsigned short* dB, int kb) {
#pragma unroll
        for (int li = 0; li < 4; ++li) {
            const int i = wave * 4 + li;
            const unsigned short* ga = Abase + (size_t)(bm * 128 + i * 8 + rin) * H_ + kb + schk * 8;
            __builtin_amdgcn_global_load_lds((gas_cvptr)ga,
                (las_vptr)(dA + i * 512 + lane * 8), 16, 0, 0);
            const unsigned short* gb = Bbase + (size_t)(bn * 128 + i * 8 + rin) * H_ + kb + schk * 8;
            __builtin_amdgcn_global_load_lds((gas_cvptr)gb,
                (las_vptr)(dB + i * 512 + lane * 8), 16, 0, 0);
        }
    };

    auto compute = [&](const unsigned short* LA, const unsigned short* LB) {
#pragma unroll
        for (int ks = 0; ks < 2; ++ks) {
            bf16x8 af[4], bfr[4];
            // logical chunk c = ks*4 + quad; physical = c ^ (row&7), row&7 == lane&7
            const int p = ((ks * 4 + (lane >> 4)) ^ (lane & 7));
#pragma unroll
            for (int i = 0; i < 4; ++i) {
                const int m = wm + i * 16 + (lane & 15);
                af[i] = *(const bf16x8*)(LA + m * 64 + p * 8);
                const int n = wn + i * 16 + (lane & 15);
                bfr[i] = *(const bf16x8*)(LB + n * 64 + p * 8);
            }
#pragma unroll
            for (int i = 0; i < 4; ++i)
#pragma unroll
                for (int j = 0; j < 4; ++j)
                    acc[i][j] = __builtin_amdgcn_mfma_f32_16x16x32_bf16(
                        af[i], bfr[j], acc[i][j], 0, 0, 0);
        }
    };

    // ---- 2-phase pipeline over 12 K-tiles ----
    stage(lds_A[0], lds_B[0], 0);
#pragma unroll 1
    for (int kt = 0; kt < 12; kt += 2) {
        // even phase: prefetch kt+1 into buf1, compute buf0
        stage(lds_A[1], lds_B[1], (kt + 1) * 64);
        asm volatile("s_waitcnt vmcnt(8)" ::: "memory");   // buf0's 8 loads done
        __builtin_amdgcn_s_barrier();
        asm volatile("" ::: "memory");
        compute(lds_A[0], lds_B[0]);
        __builtin_amdgcn_s_barrier();                      // all waves done reading buf0
        asm volatile("" ::: "memory");
        // odd phase: prefetch kt+2 into buf0 (unless last), compute buf1
        if (kt + 2 < 12) {
            stage(lds_A[0], lds_B[0], (kt + 2) * 64);
            asm volatile("s_waitcnt vmcnt(8)" ::: "memory"); // buf1's loads done
        } else {
            asm volatile("s_waitcnt vmcnt(0)" ::: "memory");
        }
        __builtin_amdgcn_s_barrier();
        asm volatile("" ::: "memory");
        compute(lds_A[1], lds_B[1]);
        __builtin_amdgcn_s_barrier();
        asm volatile("" ::: "memory");
    }

    // ---- epilogue: bias + GELU (sigmoid form: v*sigma(2u), no fp32 div) ----
    const int quad = lane >> 4;
    const int cn = lane & 15;
    float* outb = out + (size_t)b * S_ * H_;
    float biasj[4];
#pragma unroll
    for (int j = 0; j < 4; ++j)
        biasj[j] = eb[e * H_ + bn * 128 + wn + j * 16 + cn];
#pragma unroll
    for (int i = 0; i < 4; ++i) {
        const int m0 = bm * 128 + wm + i * 16 + quad * 4;
#pragma unroll
        for (int r = 0; r < 4; ++r) {
            float* rowp = outb + (size_t)(m0 + r) * H_ + bn * 128 + wn + cn;
#pragma unroll
            for (int j = 0; j < 4; ++j) {
                float v = acc[i][j][r] + biasj[j];
                // 0.5*v*(1+tanh(u)) == v * sigmoid(2u); exp arg = -2*0.79788456*(v+0.044715 v^3)
                float u = -1.5957691216057308f * v - 0.07135481627362234f * (v * v * v);
                float s = __builtin_amdgcn_rcpf(1.0f + __expf(u));
                rowp[j * 16] = v * s;
            }
        }
    }
}

extern "C" void kernel_launch(void* const* d_in, const int* in_sizes, int n_in,
                              void* d_out, int out_size, void* d_ws, size_t ws_size,
                              hipStream_t stream) {
    const float* inp   = (const float*)d_in[0];   // [32,2048,768]
    const float* gamma = (const float*)d_in[1];   // [768]
    const float* beta  = (const float*)d_in[2];   // [768]
    const float* rw    = (const float*)d_in[3];   // [768,2]
    const float* rb    = (const float*)d_in[4];   // [2]
    const float* ew    = (const float*)d_in[5];   // [2,768,768]
    const float* eb    = (const float*)d_in[6];   // [2,768]
    float* out = (float*)d_out;

    char* ws = (char*)d_ws;
    const size_t xbf_bytes = (size_t)B_ * S_ * H_ * 2;        // 100,663,296
    const size_t wt_bytes  = (size_t)E_ * H_ * H_ * 2;        //   2,359,296
    unsigned short* xbf = (unsigned short*)ws;
    unsigned short* wt  = (unsigned short*)(ws + xbf_bytes);
    float* seq_sum = (float*)(ws + xbf_bytes + wt_bytes);     // 32*768 floats
    int*   eidx    = (int*)((char*)seq_sum + (size_t)B_ * H_ * 4);
    float* psum    = (float*)((char*)eidx + 128);

    // zero seq_sum + eidx + psum region (ws is poisoned 0xAA each call)
    hipMemsetAsync(seq_sum, 0, (size_t)B_ * H_ * 4 + 128 + 16, stream);

    convert_reduce<<<B_ * 64, 192, 0, stream>>>(inp, xbf, seq_sum);
    transpose_w<<<dim3(12, 12, E_), 256, 0, stream>>>(ew, wt);
    router_kernel<<<B_, 256, 0, stream>>>(seq_sum, gamma, beta, rw, rb, eidx, psum);
    moe_gemm<<<3072, 256, 0, stream>>>(xbf, wt, eb, eidx, psum, out,
                                       out + (size_t)out_size - 1);
}